// Round 6
// baseline (997.884 us; speedup 1.0000x reference)
//
#include <hip/hip_runtime.h>
#include <hip/hip_bf16.h>
#include <cstddef>

#define Bn 2
#define Sn 2048
#define Dn 1024
#define Hn 16
#define HDn 64
static constexpr float SCALE_ = 0.125f; // 1/sqrt(64)

typedef __attribute__((ext_vector_type(8))) short short8;
typedef __attribute__((ext_vector_type(4))) float f4;

__device__ inline f4 mfma16(short8 a, short8 b, f4 c) {
  return __builtin_amdgcn_mfma_f32_16x16x32_bf16(a, b, c, 0, 0, 0);
}

typedef const __attribute__((address_space(1))) void gv_t;
typedef __attribute__((address_space(3))) void lv_t;
__device__ inline void gload_lds16(const void* g, void* l) {
  // LDS dest = wave-uniform base + lane*16B; global src is per-lane.
  __builtin_amdgcn_global_load_lds((gv_t*)g, (lv_t*)l, 16, 0, 0);
}

__device__ inline unsigned packbf2(float x, float y) {
  __bf16 a = (__bf16)x, b = (__bf16)y;
  unsigned short ua = __builtin_bit_cast(unsigned short, a);
  unsigned short ub = __builtin_bit_cast(unsigned short, b);
  return (unsigned)ua | ((unsigned)ub << 16);
}
__device__ inline float unp_lo(unsigned u) { return __builtin_bit_cast(float, u << 16); }
__device__ inline float unp_hi(unsigned u) { return __builtin_bit_cast(float, u & 0xffff0000u); }

// ---------------- f32 -> bf16 conversion (batched via grid.y) ----------------
struct CvtArgs { const float* src[7]; __bf16* dst[7]; int n[7]; };

__global__ __launch_bounds__(256) void cvt_bf16(CvtArgs a) {
  const int z = blockIdx.y;
  const float* __restrict__ s = a.src[z];
  __bf16* __restrict__ d = a.dst[z];
  const int n = a.n[z];
  for (int i = (blockIdx.x * 256 + threadIdx.x) * 8; i < n; i += gridDim.x * 256 * 8) {
    f4 x = *(const f4*)(s + i);
    f4 y = *(const f4*)(s + i + 4);
    __bf16 t[8] __attribute__((aligned(16)));
    t[0] = (__bf16)x.x; t[1] = (__bf16)x.y; t[2] = (__bf16)x.z; t[3] = (__bf16)x.w;
    t[4] = (__bf16)y.x; t[5] = (__bf16)y.y; t[6] = (__bf16)y.z; t[7] = (__bf16)y.w;
    *(short8*)(d + i) = *(short8*)t;
  }
}

// ---------------- m97-style bf16 GEMM: C = A @ W^T + bias ----------------
// A[M][K], W[N][K] bf16; 128x128 tile, BK=32, 4 waves, 4x4 acc, global_load_lds.
// mode 0: C bf16 [M][N]; 1: C f32 [M][N]; 2: C bf16 V-transposed [b][n][s]
struct GemmPtrs { const __bf16* A[3]; const __bf16* W[3]; const float* bias[3];
                  void* C[3]; int mode[3]; };

__global__ __launch_bounds__(256) void gemm128(GemmPtrs P, int M, int N, int K) {
  __shared__ __bf16 As[128 * 32];  // linear [128][32]: matches gload_lds lane order
  __shared__ __bf16 Bs[128 * 32];
  const int z = blockIdx.z;
  const __bf16* __restrict__ A = P.A[z];
  const __bf16* __restrict__ W = P.W[z];
  const float* __restrict__ bias = P.bias[z];
  const int mode = P.mode[z];
  const int tid = threadIdx.x, wid = tid >> 6, lane = tid & 63;
  const int m0 = blockIdx.y * 128, n0 = blockIdx.x * 128;
  const int wm = (wid >> 1) * 64, wn = (wid & 1) * 64;
  const int lr = lane & 15, lg = lane >> 4;
  const int srow = lane >> 2, scol = (lane & 3) * 8;  // staging lane -> (row, col8)
  f4 acc[4][4] = {};
  for (int k0 = 0; k0 < K; k0 += 32) {
    #pragma unroll
    for (int c = 0; c < 2; c++) {
      const int chunk = wid * 2 + c;  // 16-row chunk of the 128-row tile
      gload_lds16(A + (size_t)(m0 + chunk * 16 + srow) * K + k0 + scol, &As[chunk * 512]);
      gload_lds16(W + (size_t)(n0 + chunk * 16 + srow) * K + k0 + scol, &Bs[chunk * 512]);
    }
    __syncthreads();
    short8 af[4], bfr[4];
    #pragma unroll
    for (int i = 0; i < 4; i++) af[i]  = *(const short8*)&As[(wm + i * 16 + lr) * 32 + lg * 8];
    #pragma unroll
    for (int j = 0; j < 4; j++) bfr[j] = *(const short8*)&Bs[(wn + j * 16 + lr) * 32 + lg * 8];
    #pragma unroll
    for (int i = 0; i < 4; i++)
      #pragma unroll
      for (int j = 0; j < 4; j++) acc[i][j] = mfma16(af[i], bfr[j], acc[i][j]);
    __syncthreads();
  }
  #pragma unroll
  for (int i = 0; i < 4; i++) {
    #pragma unroll
    for (int j = 0; j < 4; j++) {
      const int row = m0 + wm + i * 16 + lg * 4;  // rows row..row+3
      const int col = n0 + wn + j * 16 + lr;
      const float bb = bias[col];
      if (mode == 2) {
        // Vt[b][col][s]: b = row>>11, s = row&2047 (4-aligned)
        __bf16 o[4] __attribute__((aligned(8)));
        #pragma unroll
        for (int r = 0; r < 4; r++) o[r] = (__bf16)(acc[i][j][r] + bb);
        __bf16* dst = (__bf16*)P.C[z] + ((size_t)(row >> 11) * Dn + col) * Sn + (row & 2047);
        *(ulong1*)dst = *(ulong1*)o;
      } else if (mode == 0) {
        #pragma unroll
        for (int r = 0; r < 4; r++)
          ((__bf16*)P.C[z])[(size_t)(row + r) * N + col] = (__bf16)(acc[i][j][r] + bb);
      } else {
        #pragma unroll
        for (int r = 0; r < 4; r++)
          ((float*)P.C[z])[(size_t)(row + r) * N + col] = acc[i][j][r] + bb;
      }
    }
  }
}

// ---------------- attention v2: swapped QK^T, single pass, P in registers ----------------
// Lane (lr,lg) owns q-row lr; per acc reg r it owns col lg*4+r of each 16-col tile.
__global__ __launch_bounds__(256) void attn_kernel(
    const __bf16* __restrict__ Q, const __bf16* __restrict__ Kb,
    const __bf16* __restrict__ Vt, const int* __restrict__ mask,
    float* __restrict__ attn_out, __bf16* __restrict__ ctx)
{
  __shared__ __bf16 stg[4][16][40];   // per-wave P redistribution (5 KB)
  __shared__ float red[4][16][64];    // ctx cross-wave reduce (16 KB)
  __shared__ float sums[4][16];
  __shared__ float finals[16];

  const int b = blockIdx.z, h = blockIdx.y, q0 = blockIdx.x * 16;
  const int tid = threadIdx.x, wid = tid >> 6, lane = tid & 63;
  const int lr = lane & 15, lg = lane >> 4;

  // Q fragments (16 rows x 64 k), B-operand: lane holds Q[q0+lr][lg*8..]
  const __bf16* Qbase = Q + ((size_t)(b * Sn + q0)) * Dn + h * HDn;
  const short8 qf0 = *(const short8*)(Qbase + (size_t)lr * Dn + lg * 8);
  const short8 qf1 = *(const short8*)(Qbase + (size_t)lr * Dn + 32 + lg * 8);

  const __bf16* Kbase = Kb + (size_t)b * Sn * Dn + h * HDn;
  const int* mrow = mask + b * Sn;

  // ---- Phase 1: QK^T (swapped) + exp, packed bf16 in regs; row-sum accum ----
  float ssum = 0.f;
  unsigned pr[64];  // 128 bf16 unnormalized exp values; all indices static
  #pragma unroll
  for (int ct = 0; ct < 32; ct++) {
    const int col0 = wid * 512 + ct * 16;
    const __bf16* Kp = Kbase + (size_t)(col0 + lr) * Dn + lg * 8;
    const short8 kf0 = *(const short8*)Kp;        // A-operand: K[col0+lr][k]
    const short8 kf1 = *(const short8*)(Kp + 32);
    f4 a = {0.f, 0.f, 0.f, 0.f};
    a = mfma16(kf0, qf0, a);   // D[kcol=lg*4+r][q=lr]
    a = mfma16(kf1, qf1, a);
    const int4 m4 = *(const int4*)&mrow[col0 + lg * 4];
    float p0 = m4.x ? __expf(a[0] * SCALE_) : 0.f;
    float p1 = m4.y ? __expf(a[1] * SCALE_) : 0.f;
    float p2 = m4.z ? __expf(a[2] * SCALE_) : 0.f;
    float p3 = m4.w ? __expf(a[3] * SCALE_) : 0.f;
    ssum += (p0 + p1) + (p2 + p3);
    pr[2 * ct]     = packbf2(p0, p1);
    pr[2 * ct + 1] = packbf2(p2, p3);
  }

  // ---- Phase 2: row-sum reduce (lg dim within wave, then cross-wave) ----
  ssum += __shfl_xor(ssum, 16);
  ssum += __shfl_xor(ssum, 32);
  if (lane < 16) sums[wid][lane] = ssum;
  __syncthreads();
  if (tid < 16) {
    float t = sums[0][tid] + sums[1][tid] + sums[2][tid] + sums[3][tid];
    finals[tid] = 1.0f / fmaxf(t, 1e-30f);
  }
  __syncthreads();
  const float invq = finals[lr];  // this lane's q-row normalizer

  // ---- Phase 3: attn stores (f4) + PV MFMA via per-wave LDS redistribution ----
  f4 pacc[4] = {{0.f,0.f,0.f,0.f},{0.f,0.f,0.f,0.f},{0.f,0.f,0.f,0.f},{0.f,0.f,0.f,0.f}};
  const __bf16* Vtb = Vt + ((size_t)(b * Hn + h)) * HDn * Sn;
  float* arow = attn_out + (((size_t)(b * Hn + h)) * Sn + q0 + lr) * Sn;
  #pragma unroll
  for (int c = 0; c < 16; c++) {
    const int cols0 = wid * 512 + c * 32;
    // stage this lane's 8 bf16 (k = cols0+lg*4.. and cols0+16+lg*4..) into P[q=lr][k]
    uint2 w0 = make_uint2(pr[4 * c], pr[4 * c + 1]);
    uint2 w1 = make_uint2(pr[4 * c + 2], pr[4 * c + 3]);
    *(uint2*)&stg[wid][lr][lg * 4]      = w0;
    *(uint2*)&stg[wid][lr][16 + lg * 4] = w1;
    // wave-internal LDS RAW (in-order DS pipeline within a wave)
    const short8 af = *(const short8*)&stg[wid][lr][lg * 8];  // P[q=lr][k=lg*8..]
    #pragma unroll
    for (int nt = 0; nt < 4; nt++) {
      const short8 bfr = *(const short8*)(Vtb + (size_t)(nt * 16 + lr) * Sn + cols0 + lg * 8);
      pacc[nt] = mfma16(af, bfr, pacc[nt]);  // D[q=lg*4+r][hd=lr]
    }
    // normalized attn output: 2 x f4 per lane, rows=lr, cols contiguous
    f4 v0 = { unp_lo(pr[4*c]) * invq,   unp_hi(pr[4*c]) * invq,
              unp_lo(pr[4*c+1]) * invq, unp_hi(pr[4*c+1]) * invq };
    f4 v1 = { unp_lo(pr[4*c+2]) * invq, unp_hi(pr[4*c+2]) * invq,
              unp_lo(pr[4*c+3]) * invq, unp_hi(pr[4*c+3]) * invq };
    *(f4*)&arow[cols0 + lg * 4]      = v0;
    *(f4*)&arow[cols0 + 16 + lg * 4] = v1;
  }
  __syncthreads();

  // ---- Phase 4: cross-wave ctx reduce (normalize while writing) ----
  #pragma unroll
  for (int nt = 0; nt < 4; nt++)
    #pragma unroll
    for (int r = 0; r < 4; r++)
      red[wid][lg * 4 + r][nt * 16 + lr] = pacc[nt][r] * finals[lg * 4 + r];
  __syncthreads();
  const int q = tid >> 4, c0 = (tid & 15) * 4;
  __bf16* crow = ctx + ((size_t)(b * Sn + q0 + q)) * Dn + h * HDn + c0;
  __bf16 o[4] __attribute__((aligned(8)));
  #pragma unroll
  for (int j = 0; j < 4; j++) {
    float v = red[0][q][c0 + j] + red[1][q][c0 + j] + red[2][q][c0 + j] + red[3][q][c0 + j];
    o[j] = (__bf16)v;
  }
  *(ulong1*)crow = *(ulong1*)o;
}

// ---------------- launch ----------------
// d_ws (40 MB): Wbf (8) | Qb (8) | Kbf (8) | Vt (8) | ctx (8)
// attn output region doubles as scratch for converted activations (overwritten later).
extern "C" void kernel_launch(void* const* d_in, const int* in_sizes, int n_in,
                              void* d_out, int out_size, void* d_ws, size_t ws_size,
                              hipStream_t stream) {
  const float* query = (const float*)d_in[0];
  const float* key   = (const float*)d_in[1];
  const float* value = (const float*)d_in[2];
  const int*   mask  = (const int*)d_in[3];
  const float* wq = (const float*)d_in[4];
  const float* bq = (const float*)d_in[5];
  const float* wk = (const float*)d_in[6];
  const float* bk = (const float*)d_in[7];
  const float* wv = (const float*)d_in[8];
  const float* bv = (const float*)d_in[9];
  const float* wo = (const float*)d_in[10];
  const float* bo = (const float*)d_in[11];

  float* out  = (float*)d_out;
  float* attn = out + (size_t)Bn * Sn * Dn;

  const size_t NA = (size_t)4194304;  // 4096*1024
  const size_t NW = (size_t)1048576;  // 1024*1024
  __bf16* Wbf  = (__bf16*)d_ws;
  __bf16* Qb   = Wbf + 4 * NW;
  __bf16* Kbf  = Qb + NA;
  __bf16* Vtb  = Kbf + NA;
  __bf16* ctxb = Vtb + NA;
  // scratch inside the attn output region (537 MB; fully overwritten by attn_kernel)
  __bf16* cQ = (__bf16*)attn;
  __bf16* cK = cQ + NA;
  __bf16* cV = cK + NA;

  // 1) convert weights + all activations
  CvtArgs c7;
  c7.src[0] = wq;    c7.dst[0] = Wbf;          c7.n[0] = (int)NW;
  c7.src[1] = wk;    c7.dst[1] = Wbf + NW;     c7.n[1] = (int)NW;
  c7.src[2] = wv;    c7.dst[2] = Wbf + 2 * NW; c7.n[2] = (int)NW;
  c7.src[3] = wo;    c7.dst[3] = Wbf + 3 * NW; c7.n[3] = (int)NW;
  c7.src[4] = query; c7.dst[4] = cQ;           c7.n[4] = (int)NA;
  c7.src[5] = key;   c7.dst[5] = cK;           c7.n[5] = (int)NA;
  c7.src[6] = value; c7.dst[6] = cV;           c7.n[6] = (int)NA;
  cvt_bf16<<<dim3(256, 7), 256, 0, stream>>>(c7);

  // 2) Q, K, V projections fused (grid.z = 3; V gets transposed epilogue)
  GemmPtrs g3;
  g3.A[0] = cQ; g3.W[0] = Wbf;          g3.bias[0] = bq; g3.C[0] = Qb;  g3.mode[0] = 0;
  g3.A[1] = cK; g3.W[1] = Wbf + NW;     g3.bias[1] = bk; g3.C[1] = Kbf; g3.mode[1] = 0;
  g3.A[2] = cV; g3.W[2] = Wbf + 2 * NW; g3.bias[2] = bv; g3.C[2] = Vtb; g3.mode[2] = 2;
  gemm128<<<dim3(8, 32, 3), 256, 0, stream>>>(g3, 4096, 1024, 1024);

  // 3) attention (writes full attn f32 output + ctx bf16)
  attn_kernel<<<dim3(128, 16, 2), 256, 0, stream>>>(Qb, Kbf, Vtb, mask, attn, ctxb);

  // 4) output projection (f32 out)
  GemmPtrs go;
  go.A[0] = ctxb; go.W[0] = Wbf + 3 * NW; go.bias[0] = bo; go.C[0] = out; go.mode[0] = 1;
  go.A[1] = go.A[0]; go.W[1] = go.W[0]; go.bias[1] = go.bias[0]; go.C[1] = go.C[0]; go.mode[1] = 1;
  go.A[2] = go.A[0]; go.W[2] = go.W[0]; go.bias[2] = go.bias[0]; go.C[2] = go.C[0]; go.mode[2] = 1;
  gemm128<<<dim3(8, 32, 1), 256, 0, stream>>>(go, 4096, 1024, 1024);
}

// Round 8
// 907.466 us; speedup vs baseline: 1.0996x; 1.0996x over previous
//
#include <hip/hip_runtime.h>
#include <hip/hip_bf16.h>
#include <cstddef>

#define Bn 2
#define Sn 2048
#define Dn 1024
#define Hn 16
#define HDn 64
static constexpr float SCALE_ = 0.125f; // 1/sqrt(64)

typedef __attribute__((ext_vector_type(8))) short short8;
typedef __attribute__((ext_vector_type(4))) float f4;

__device__ inline f4 mfma16(short8 a, short8 b, f4 c) {
  return __builtin_amdgcn_mfma_f32_16x16x32_bf16(a, b, c, 0, 0, 0);
}

typedef const __attribute__((address_space(1))) void gv_t;
typedef __attribute__((address_space(3))) void lv_t;
__device__ inline void gload_lds16(const void* g, void* l) {
  // LDS dest = wave-uniform base + lane*16B; global src is per-lane.
  __builtin_amdgcn_global_load_lds((gv_t*)g, (lv_t*)l, 16, 0, 0);
}

__device__ inline unsigned packbf2(float x, float y) {
  __bf16 a = (__bf16)x, b = (__bf16)y;
  unsigned short ua = __builtin_bit_cast(unsigned short, a);
  unsigned short ub = __builtin_bit_cast(unsigned short, b);
  return (unsigned)ua | ((unsigned)ub << 16);
}
__device__ inline float unp_lo(unsigned u) { return __builtin_bit_cast(float, u << 16); }
__device__ inline float unp_hi(unsigned u) { return __builtin_bit_cast(float, u & 0xffff0000u); }

// ---------------- f32 -> bf16 conversion (batched via grid.y) ----------------
struct CvtArgs { const float* src[7]; __bf16* dst[7]; int n[7]; };

__global__ __launch_bounds__(256) void cvt_bf16(CvtArgs a) {
  const int z = blockIdx.y;
  const float* __restrict__ s = a.src[z];
  __bf16* __restrict__ d = a.dst[z];
  const int n = a.n[z];
  for (int i = (blockIdx.x * 256 + threadIdx.x) * 8; i < n; i += gridDim.x * 256 * 8) {
    f4 x = *(const f4*)(s + i);
    f4 y = *(const f4*)(s + i + 4);
    __bf16 t[8] __attribute__((aligned(16)));
    t[0] = (__bf16)x.x; t[1] = (__bf16)x.y; t[2] = (__bf16)x.z; t[3] = (__bf16)x.w;
    t[4] = (__bf16)y.x; t[5] = (__bf16)y.y; t[6] = (__bf16)y.z; t[7] = (__bf16)y.w;
    *(short8*)(d + i) = *(short8*)t;
  }
}

// ---------------- m97-style bf16 GEMM: C = A @ W^T + bias ----------------
// A[M][K], W[N][K] bf16; 128x128 tile, BK=32, 4 waves, 4x4 acc, global_load_lds.
// mode 0: C bf16 [M][N]; 1: C f32 [M][N]; 2: C bf16 V-transposed [b][n][s]
struct GemmPtrs { const __bf16* A[3]; const __bf16* W[3]; const float* bias[3];
                  void* C[3]; int mode[3]; };

__global__ __launch_bounds__(256) void gemm128(GemmPtrs P, int M, int N, int K) {
  __shared__ __bf16 As[128 * 32];  // linear [128][32]: matches gload_lds lane order
  __shared__ __bf16 Bs[128 * 32];
  const int z = blockIdx.z;
  const __bf16* __restrict__ A = P.A[z];
  const __bf16* __restrict__ W = P.W[z];
  const float* __restrict__ bias = P.bias[z];
  const int mode = P.mode[z];
  const int tid = threadIdx.x, wid = tid >> 6, lane = tid & 63;
  const int m0 = blockIdx.y * 128, n0 = blockIdx.x * 128;
  const int wm = (wid >> 1) * 64, wn = (wid & 1) * 64;
  const int lr = lane & 15, lg = lane >> 4;
  const int srow = lane >> 2, scol = (lane & 3) * 8;  // staging lane -> (row, col8)
  f4 acc[4][4] = {};
  for (int k0 = 0; k0 < K; k0 += 32) {
    #pragma unroll
    for (int c = 0; c < 2; c++) {
      const int chunk = wid * 2 + c;  // 16-row chunk of the 128-row tile
      gload_lds16(A + (size_t)(m0 + chunk * 16 + srow) * K + k0 + scol, &As[chunk * 512]);
      gload_lds16(W + (size_t)(n0 + chunk * 16 + srow) * K + k0 + scol, &Bs[chunk * 512]);
    }
    __syncthreads();
    short8 af[4], bfr[4];
    #pragma unroll
    for (int i = 0; i < 4; i++) af[i]  = *(const short8*)&As[(wm + i * 16 + lr) * 32 + lg * 8];
    #pragma unroll
    for (int j = 0; j < 4; j++) bfr[j] = *(const short8*)&Bs[(wn + j * 16 + lr) * 32 + lg * 8];
    #pragma unroll
    for (int i = 0; i < 4; i++)
      #pragma unroll
      for (int j = 0; j < 4; j++) acc[i][j] = mfma16(af[i], bfr[j], acc[i][j]);
    __syncthreads();
  }
  #pragma unroll
  for (int i = 0; i < 4; i++) {
    #pragma unroll
    for (int j = 0; j < 4; j++) {
      const int row = m0 + wm + i * 16 + lg * 4;  // rows row..row+3
      const int col = n0 + wn + j * 16 + lr;
      const float bb = bias[col];
      if (mode == 2) {
        // Vt[b][col][s]: b = row>>11, s = row&2047 (4-aligned)
        __bf16 o[4] __attribute__((aligned(8)));
        #pragma unroll
        for (int r = 0; r < 4; r++) o[r] = (__bf16)(acc[i][j][r] + bb);
        __bf16* dst = (__bf16*)P.C[z] + ((size_t)(row >> 11) * Dn + col) * Sn + (row & 2047);
        *(ulong1*)dst = *(ulong1*)o;
      } else if (mode == 0) {
        #pragma unroll
        for (int r = 0; r < 4; r++)
          ((__bf16*)P.C[z])[(size_t)(row + r) * N + col] = (__bf16)(acc[i][j][r] + bb);
      } else {
        #pragma unroll
        for (int r = 0; r < 4; r++)
          ((float*)P.C[z])[(size_t)(row + r) * N + col] = acc[i][j][r] + bb;
      }
    }
  }
}

// ---------------- attention v3: swapped QK^T, single pass, 8 waves x 256 cols ----------------
// Lane (lr,lg) of wave wid: QK^T D[q=lr][k=col0+lg*4+r]; PV D[q=lg*4+r][hd=nt*16+lr].
__global__ __launch_bounds__(512, 4) void attn_kernel(
    const __bf16* __restrict__ Q, const __bf16* __restrict__ Kb,
    const __bf16* __restrict__ Vt, const int* __restrict__ mask,
    float* __restrict__ attn_out, __bf16* __restrict__ ctx)
{
  __shared__ __bf16 stg[8][16][40];   // per-wave P redistribution (10 KB)
  __shared__ float red[8][16][64];    // ctx cross-wave reduce (32 KB)
  __shared__ float sums[8][16];
  __shared__ float finals[16];

  const int b = blockIdx.z, h = blockIdx.y, q0 = blockIdx.x * 16;
  const int tid = threadIdx.x, wid = tid >> 6, lane = tid & 63;
  const int lr = lane & 15, lg = lane >> 4;

  // Q fragments (16 rows x 64 k), B-operand: lane holds Q[q0+lr][lg*8..]
  const __bf16* Qbase = Q + ((size_t)(b * Sn + q0)) * Dn + h * HDn;
  const short8 qf0 = *(const short8*)(Qbase + (size_t)lr * Dn + lg * 8);
  const short8 qf1 = *(const short8*)(Qbase + (size_t)lr * Dn + 32 + lg * 8);

  const __bf16* Kbase = Kb + (size_t)b * Sn * Dn + h * HDn;
  const int* mrow = mask + b * Sn;

  // ---- Phase 1: QK^T (swapped) + exp, packed bf16 in regs; row-sum accum ----
  float ssum = 0.f;
  unsigned pr[32];  // 64 bf16 unnormalized exp values; all indices static
  #pragma unroll
  for (int ct = 0; ct < 16; ct++) {
    const int col0 = wid * 256 + ct * 16;
    const __bf16* Kp = Kbase + (size_t)(col0 + lr) * Dn + lg * 8;
    const short8 kf0 = *(const short8*)Kp;        // A-operand: K[col0+lr][k]
    const short8 kf1 = *(const short8*)(Kp + 32);
    f4 a = {0.f, 0.f, 0.f, 0.f};
    a = mfma16(kf0, qf0, a);   // D[q=lr][kcol=lg*4+r]
    a = mfma16(kf1, qf1, a);
    const int4 m4 = *(const int4*)&mrow[col0 + lg * 4];
    float p0 = m4.x ? __expf(a[0] * SCALE_) : 0.f;
    float p1 = m4.y ? __expf(a[1] * SCALE_) : 0.f;
    float p2 = m4.z ? __expf(a[2] * SCALE_) : 0.f;
    float p3 = m4.w ? __expf(a[3] * SCALE_) : 0.f;
    ssum += (p0 + p1) + (p2 + p3);
    pr[2 * ct]     = packbf2(p0, p1);
    pr[2 * ct + 1] = packbf2(p2, p3);
  }

  // ---- Phase 2: row-sum reduce (across lg within wave, then cross-wave) ----
  ssum += __shfl_xor(ssum, 16);
  ssum += __shfl_xor(ssum, 32);
  if (lane < 16) sums[wid][lane] = ssum;
  __syncthreads();
  if (tid < 16) {
    float t = 0.f;
    #pragma unroll
    for (int w = 0; w < 8; w++) t += sums[w][tid];
    finals[tid] = 1.0f / fmaxf(t, 1e-30f);
  }
  __syncthreads();
  const float invq = finals[lr];  // this lane's q-row normalizer

  // ---- Phase 3: attn stores (f4) + PV MFMA via per-wave LDS redistribution ----
  f4 pacc[4] = {{0.f,0.f,0.f,0.f},{0.f,0.f,0.f,0.f},{0.f,0.f,0.f,0.f},{0.f,0.f,0.f,0.f}};
  const __bf16* Vtb = Vt + ((size_t)(b * Hn + h)) * HDn * Sn;
  float* arow = attn_out + (((size_t)(b * Hn + h)) * Sn + q0 + lr) * Sn;
  #pragma unroll
  for (int c = 0; c < 8; c++) {
    const int cols0 = wid * 256 + c * 32;
    // stage this lane's 8 bf16 (k = cols0+lg*4.. and cols0+16+lg*4..) into P[q=lr][k]
    uint2 w0 = make_uint2(pr[4 * c], pr[4 * c + 1]);
    uint2 w1 = make_uint2(pr[4 * c + 2], pr[4 * c + 3]);
    *(uint2*)&stg[wid][lr][lg * 4]      = w0;
    *(uint2*)&stg[wid][lr][16 + lg * 4] = w1;
    // wave-internal LDS RAW (in-order DS pipeline within a wave)
    const short8 af = *(const short8*)&stg[wid][lr][lg * 8];  // P[q=lr][k=lg*8..]
    #pragma unroll
    for (int nt = 0; nt < 4; nt++) {
      const short8 bfr = *(const short8*)(Vtb + (size_t)(nt * 16 + lr) * Sn + cols0 + lg * 8);
      pacc[nt] = mfma16(af, bfr, pacc[nt]);  // D[q=lg*4+r][hd=nt*16+lr]
    }
    // normalized attn output: 2 x f4 per lane, row=lr, cols contiguous
    f4 v0 = { unp_lo(pr[4*c]) * invq,   unp_hi(pr[4*c]) * invq,
              unp_lo(pr[4*c+1]) * invq, unp_hi(pr[4*c+1]) * invq };
    f4 v1 = { unp_lo(pr[4*c+2]) * invq, unp_hi(pr[4*c+2]) * invq,
              unp_lo(pr[4*c+3]) * invq, unp_hi(pr[4*c+3]) * invq };
    *(f4*)&arow[cols0 + lg * 4]      = v0;
    *(f4*)&arow[cols0 + 16 + lg * 4] = v1;
  }
  __syncthreads();

  // ---- Phase 4: cross-wave ctx reduce (normalize while writing) ----
  #pragma unroll
  for (int nt = 0; nt < 4; nt++)
    #pragma unroll
    for (int r = 0; r < 4; r++)
      red[wid][lg * 4 + r][nt * 16 + lr] = pacc[nt][r] * finals[lg * 4 + r];
  __syncthreads();
  const int q = tid >> 5, c0 = (tid & 31) * 2;
  float v0 = 0.f, v1 = 0.f;
  #pragma unroll
  for (int w = 0; w < 8; w++) { v0 += red[w][q][c0]; v1 += red[w][q][c0 + 1]; }
  unsigned* crow = (unsigned*)(ctx + ((size_t)(b * Sn + q0 + q)) * Dn + h * HDn + c0);
  *crow = packbf2(v0, v1);
}

// ---------------- launch ----------------
// d_ws (40 MB): Wbf (8) | Qb (8) | Kbf (8) | Vt (8) | ctx (8)
// attn output region doubles as scratch for converted activations (overwritten later).
extern "C" void kernel_launch(void* const* d_in, const int* in_sizes, int n_in,
                              void* d_out, int out_size, void* d_ws, size_t ws_size,
                              hipStream_t stream) {
  const float* query = (const float*)d_in[0];
  const float* key   = (const float*)d_in[1];
  const float* value = (const float*)d_in[2];
  const int*   mask  = (const int*)d_in[3];
  const float* wq = (const float*)d_in[4];
  const float* bq = (const float*)d_in[5];
  const float* wk = (const float*)d_in[6];
  const float* bk = (const float*)d_in[7];
  const float* wv = (const float*)d_in[8];
  const float* bv = (const float*)d_in[9];
  const float* wo = (const float*)d_in[10];
  const float* bo = (const float*)d_in[11];

  float* out  = (float*)d_out;
  float* attn = out + (size_t)Bn * Sn * Dn;

  const size_t NA = (size_t)4194304;  // 4096*1024
  const size_t NW = (size_t)1048576;  // 1024*1024
  __bf16* Wbf  = (__bf16*)d_ws;
  __bf16* Qb   = Wbf + 4 * NW;
  __bf16* Kbf  = Qb + NA;
  __bf16* Vtb  = Kbf + NA;
  __bf16* ctxb = Vtb + NA;
  // scratch inside the attn output region (537 MB; fully overwritten by attn_kernel)
  __bf16* cQ = (__bf16*)attn;
  __bf16* cK = cQ + NA;
  __bf16* cV = cK + NA;

  // 1) convert weights + all activations
  CvtArgs c7;
  c7.src[0] = wq;    c7.dst[0] = Wbf;          c7.n[0] = (int)NW;
  c7.src[1] = wk;    c7.dst[1] = Wbf + NW;     c7.n[1] = (int)NW;
  c7.src[2] = wv;    c7.dst[2] = Wbf + 2 * NW; c7.n[2] = (int)NW;
  c7.src[3] = wo;    c7.dst[3] = Wbf + 3 * NW; c7.n[3] = (int)NW;
  c7.src[4] = query; c7.dst[4] = cQ;           c7.n[4] = (int)NA;
  c7.src[5] = key;   c7.dst[5] = cK;           c7.n[5] = (int)NA;
  c7.src[6] = value; c7.dst[6] = cV;           c7.n[6] = (int)NA;
  cvt_bf16<<<dim3(256, 7), 256, 0, stream>>>(c7);

  // 2) Q, K, V projections fused (grid.z = 3; V gets transposed epilogue)
  GemmPtrs g3;
  g3.A[0] = cQ; g3.W[0] = Wbf;          g3.bias[0] = bq; g3.C[0] = Qb;  g3.mode[0] = 0;
  g3.A[1] = cK; g3.W[1] = Wbf + NW;     g3.bias[1] = bk; g3.C[1] = Kbf; g3.mode[1] = 0;
  g3.A[2] = cV; g3.W[2] = Wbf + 2 * NW; g3.bias[2] = bv; g3.C[2] = Vtb; g3.mode[2] = 2;
  gemm128<<<dim3(8, 32, 3), 256, 0, stream>>>(g3, 4096, 1024, 1024);

  // 3) attention (writes full attn f32 output + ctx bf16)
  attn_kernel<<<dim3(128, 16, 2), 512, 0, stream>>>(Qb, Kbf, Vtb, mask, attn, ctxb);

  // 4) output projection (f32 out)
  GemmPtrs go;
  go.A[0] = ctxb; go.W[0] = Wbf + 3 * NW; go.bias[0] = bo; go.C[0] = out; go.mode[0] = 1;
  go.A[1] = go.A[0]; go.W[1] = go.W[0]; go.bias[1] = go.bias[0]; go.C[1] = go.C[0]; go.mode[1] = 1;
  go.A[2] = go.A[0]; go.W[2] = go.W[0]; go.bias[2] = go.bias[0]; go.C[2] = go.C[0]; go.mode[2] = 1;
  gemm128<<<dim3(8, 32, 1), 256, 0, stream>>>(go, 4096, 1024, 1024);
}